// Round 14
// baseline (9497.630 us; speedup 1.0000x reference)
//
#include <hip/hip_runtime.h>

#define BB 16
#define NN 2048
#define NITERS 100

// k = log2(e)/eps, eps = 0.05
#define K2E      28.853900817779268f
#define TWO_K2E  57.707801635558536f
#define INV2K    0.017328679513998632f   // 1/(2k)
#define INV_K2E  0.034657359027997264f
#define INV4K    0.008664339756999316f   // 1/(4k)
#define LMU      (-11.0f)                // log2(1/2048)

#if __has_builtin(__builtin_amdgcn_exp2f)
#define EXP2F(x) __builtin_amdgcn_exp2f(x)
#else
#define EXP2F(x) exp2f(x)
#endif

typedef float v2f __attribute__((ext_vector_type(2)));

// device-coherent (LLC-homed, sc1) accessors for the dual arrays
#define DSTORE(p, v) __hip_atomic_store((p), (v), __ATOMIC_RELAXED, __HIP_MEMORY_SCOPE_AGENT)
#define DLOAD(p)     __hip_atomic_load((p), __ATOMIC_RELAXED, __HIP_MEMORY_SCOPE_AGENT)

// Sum-pass, wave-autonomous: 8 rows/wave (coords from LDS), own j-half of
// LDS SoA tables; dual read directly from LLC (sc1, 16 preloads). Pair
// combine via double-buffered pcomb + LDS flag handshake (workgroup scope)
// — NO block-wide sync. Returns combined row-sum on lanes 0..7.
__device__ __forceinline__ float sumpassW(
    const float* __restrict__ u0, const float* __restrict__ u1,
    const float* __restrict__ u2,
    const float* __restrict__ t0, const float* __restrict__ t1,
    const float* __restrict__ t2, const float* __restrict__ gd,
    int rloc, int jh, int lane, int w, int tag,
    float* pcomb, int* pflag)
{
    const int jb = (jh << 10) + lane;
    float dv[16];
    #pragma unroll
    for (int s = 0; s < 16; ++s)
        dv[s] = DLOAD(gd + jb + (s << 6));

    v2f xp0[4], xp1[4], xp2[4], acc2[4];
    #pragma unroll
    for (int p = 0; p < 4; ++p) {
        xp0[p] = (v2f){u0[rloc + 2*p] * INV2K, u0[rloc + 2*p + 1] * INV2K};
        xp1[p] = (v2f){u1[rloc + 2*p] * INV2K, u1[rloc + 2*p + 1] * INV2K};
        xp2[p] = (v2f){u2[rloc + 2*p] * INV2K, u2[rloc + 2*p + 1] * INV2K};
        acc2[p] = (v2f){0.f, 0.f};
    }
    #pragma unroll 2
    for (int s = 0; s < 16; ++s) {
        const int p = jb + (s << 6);
        const float a0 = t0[p], a1 = t1[p], a2 = t2[p], ad = dv[s];
        const v2f a0v = (v2f){a0, a0}, a1v = (v2f){a1, a1};
        const v2f a2v = (v2f){a2, a2}, adv = (v2f){ad, ad};
        #pragma unroll
        for (int q = 0; q < 4; ++q) {
            v2f d = __builtin_elementwise_fma(xp0[q], a0v,
                    __builtin_elementwise_fma(xp1[q], a1v,
                    __builtin_elementwise_fma(xp2[q], a2v, adv)));
            acc2[q] += (v2f){EXP2F(d.x), EXP2F(d.y)};
        }
    }
    float acc[8];
    #pragma unroll
    for (int p = 0; p < 4; ++p) { acc[2*p] = acc2[p].x; acc[2*p+1] = acc2[p].y; }
    // multi-value butterfly (verified R3/R5/R8); lanes<8 end with row rr
    const bool b0 = lane & 1, b1 = lane & 2, b2 = lane & 4;
    float v4[4], v2_[2], v1;
    #pragma unroll
    for (int i = 0; i < 4; ++i) {
        float recv = __shfl_xor(b0 ? acc[i] : acc[i+4], 1, 64);
        v4[i] = (b0 ? acc[i+4] : acc[i]) + recv;
    }
    #pragma unroll
    for (int i = 0; i < 2; ++i) {
        float recv = __shfl_xor(b1 ? v4[i] : v4[i+2], 2, 64);
        v2_[i] = (b1 ? v4[i+2] : v4[i]) + recv;
    }
    {
        float recv = __shfl_xor(b2 ? v2_[0] : v2_[1], 4, 64);
        v1 = (b2 ? v2_[1] : v2_[0]) + recv;
    }
    v1 += __shfl_xor(v1, 8, 64);
    v1 += __shfl_xor(v1, 16, 64);
    v1 += __shfl_xor(v1, 32, 64);
    const int rr = ((lane & 1) << 2) | (lane & 2) | ((lane >> 2) & 1);
    // pair handshake: publish my partial, poll partner's (double-buffered)
    const int buf = (tag & 1);
    if (lane < 8) pcomb[buf * 128 + w * 8 + rr] = v1;
    if (lane == 0)
        __hip_atomic_store(&pflag[buf * 16 + w], tag, __ATOMIC_RELEASE,
                           __HIP_MEMORY_SCOPE_WORKGROUP);
    const int pw = w ^ 1;
    while (__hip_atomic_load(&pflag[buf * 16 + pw], __ATOMIC_ACQUIRE,
                             __HIP_MEMORY_SCOPE_WORKGROUP) < tag)
        __builtin_amdgcn_s_sleep(1);
    float S = 0.f;
    if (lane < 8) S = v1 + pcomb[buf * 128 + pw * 8 + rr];
    return S;
}

// Epilogue partial (R13-verified): sum_j P_ij*C_ij, 8 rows x own j-half.
__device__ __forceinline__ float epilG(
    const float* __restrict__ u0, const float* __restrict__ u1,
    const float* __restrict__ u2,
    const float* __restrict__ t0, const float* __restrict__ t1,
    const float* __restrict__ t2, const float* __restrict__ gB,
    float Aval, int rloc, int jh, int lane)
{
    const int jb = (jh << 10) + lane;
    float dv[16];
    #pragma unroll
    for (int s = 0; s < 16; ++s)
        dv[s] = DLOAD(gB + jb + (s << 6));

    float xr0[8], xr1[8], xr2[8], Ak[8], x2k[8];
    #pragma unroll
    for (int k = 0; k < 8; ++k) {
        xr0[k] = u0[rloc + k] * INV2K;
        xr1[k] = u1[rloc + k] * INV2K;
        xr2[k] = u2[rloc + k] * INV2K;
        const int src = ((k & 1) << 2) | (k & 2) | ((k >> 2) & 1);
        Ak[k]  = __shfl(Aval, src, 64);
        x2k[k] = K2E * (xr0[k]*xr0[k] + xr1[k]*xr1[k] + xr2[k]*xr2[k]);
    }
    float acc = 0.f;
    for (int s = 0; s < 16; ++s) {
        const int p = jb + (s << 6);
        const float a0 = t0[p], a1 = t1[p], a2 = t2[p], tb = dv[s];
        const float q2 = (a0*a0 + a1*a1 + a2*a2) * INV4K;   // k|y|^2
        #pragma unroll
        for (int k = 0; k < 8; ++k) {
            float d = fmaf(xr0[k], a0, fmaf(xr1[k], a1, fmaf(xr2[k], a2, tb)));
            float P = EXP2F(d + Ak[k]);                       // exp(logP)
            float C = fmaxf((x2k[k] + q2 - (d - tb)) * INV_K2E, 0.f);
            acc = fmaf(P, C, acc);
        }
    }
    return acc;
}

// grid: 256 blocks x 1024 threads (1 block/CU). pair-of-batches = blk&7.
// R13 schedule (1 compute phase of slack before every wait), but ZERO
// block-wide syncs in the steady loop: per-PAIR global flags (256 slots x
// 16 B per batch; jh==0 wave release-posts its own slot after its 8 sc1 Af
// stores), per-WAVE waiting (4 sc1 loads/lane + min + ballot over all 256
// slots), pair-local LDS handshake inside sumpassW. WAR safety: a pair's
// post follows its partner's butterfly, which consumed all dv loads.
__global__ __launch_bounds__(1024) void emd_sinkhorn(
    const float* __restrict__ x, const float* __restrict__ y,
    float* __restrict__ Af, float* __restrict__ Bf,
    int* __restrict__ flags, float* __restrict__ out)
{
    extern __shared__ float S[];     // 12*NN floats = 96 KB
    __shared__ float pcomb[2 * 16 * 8];
    __shared__ int   pflag[2 * 16];
    __shared__ float wsum[16];

    const int tid  = threadIdx.x;
    const int lane = tid & 63;
    const int w    = tid >> 6;        // 0..15
    const int pr   = w >> 1;          // wave-pair 0..7
    const int jh   = w & 1;           // j-half
    const int blk  = blockIdx.x;
    const int pair = blk & 7;         // = XCD id under round-robin (perf only)
    const int q    = blk >> 3;        // 0..31: row-slice within pair
    const int b0   = pair * 2, b1 = b0 + 1;
    const int base0 = b0 * NN, base1 = b1 * NN;
    const int rloc  = q * 64 + pr * 8;      // within-batch row base
    const int slot  = q * 8 + pr;           // my pair's flag slot (0..255)
    int* f0 = flags + b0 * 1024;      // 256 slots x 16 B per batch
    int* f1 = flags + b1 * 1024;

    // LDS carve: per batch 6 table slots of NN floats (SoA — conflict-free)
    float *sy00 = S,            *sy10 = S +  1*NN, *sy20 = S +  2*NN;
    float *sx00 = S +  3*NN,    *sx10 = S +  4*NN, *sx20 = S +  5*NN;
    float *sy01 = S +  6*NN,    *sy11 = S +  7*NN, *sy21 = S +  8*NN;
    float *sx01 = S +  9*NN,    *sx11 = S + 10*NN, *sx21 = S + 11*NN;

    // ---- prologue: stage 2k-scaled tables; zero pair flags ----
    if (tid < 32) pflag[tid] = 0;
    #pragma unroll
    for (int v = 0; v < 2; ++v) {
        const int p = tid + (v << 10);
        {
            const float* px = x + 3 * (size_t)(base0 + p);
            sx00[p] = TWO_K2E * px[0]; sx10[p] = TWO_K2E * px[1]; sx20[p] = TWO_K2E * px[2];
            const float* py = y + 3 * (size_t)(base0 + p);
            sy00[p] = TWO_K2E * py[0]; sy10[p] = TWO_K2E * py[1]; sy20[p] = TWO_K2E * py[2];
        }
        {
            const float* px = x + 3 * (size_t)(base1 + p);
            sx01[p] = TWO_K2E * px[0]; sx11[p] = TWO_K2E * px[1]; sx21[p] = TWO_K2E * px[2];
            const float* py = y + 3 * (size_t)(base1 + p);
            sy01[p] = TWO_K2E * py[0]; sy11[p] = TWO_K2E * py[1]; sy21[p] = TWO_K2E * py[2];
        }
    }
    // ---- prologue: B0-init for own 64 columns of both batches (sc1) ----
    if (tid < 128) {
        const int bb  = tid >> 6;
        const int col = q * 64 + (tid & 63);
        const int bs  = bb ? base1 : base0;
        const float* py = y + 3 * (size_t)(bs + col);
        const float a = py[0], b = py[1], c = py[2];
        DSTORE(&Bf[bs + col], -K2E * (a*a + b*b + c*c));
    }
    __syncthreads();                  // drains all table + B-init stores
    if (w == 0 && lane < 16) {        // post value 1 for all 8 pairs, both batches
        int* arr = (lane < 8) ? f0 : f1;
        __hip_atomic_store(arr + (q * 8 + (lane & 7)) * 4, 1, __ATOMIC_RELEASE,
                           __HIP_MEMORY_SCOPE_AGENT);
    }

    const int rr = ((lane & 1) << 2) | (lane & 2) | ((lane >> 2) & 1);

    // per-wave wait: all 256 slots of arr >= tgt (4 sc1 loads/lane, ballot)
    #define WAITW(arr, tgt) do {                                                \
        for (;;) {                                                              \
            int a_ = __hip_atomic_load((arr) + lane * 4,          __ATOMIC_RELAXED, __HIP_MEMORY_SCOPE_AGENT); \
            int b_ = __hip_atomic_load((arr) + (lane +  64) * 4,  __ATOMIC_RELAXED, __HIP_MEMORY_SCOPE_AGENT); \
            int c_ = __hip_atomic_load((arr) + (lane + 128) * 4,  __ATOMIC_RELAXED, __HIP_MEMORY_SCOPE_AGENT); \
            int d_ = __hip_atomic_load((arr) + (lane + 192) * 4,  __ATOMIC_RELAXED, __HIP_MEMORY_SCOPE_AGENT); \
            int m_ = min(min(a_, b_), min(c_, d_));                             \
            if (__ballot(m_ >= (tgt)) == ~0ULL) break;                          \
            __builtin_amdgcn_s_sleep(1);                                        \
        } } while (0)

    // post my pair's slot (jh==0 wave; release drains its 8 Af/Bf stores)
    #define POSTW(arr, val) do {                                                \
        if (jh == 0 && lane == 0)                                               \
            __hip_atomic_store((arr) + slot * 4, (val), __ATOMIC_RELEASE,       \
                               __HIP_MEMORY_SCOPE_AGENT);                       \
    } while (0)

    float Aval0 = 0.f, Aval1 = 0.f;

    for (int it = 0; it < NITERS; ++it) {
        // ---- fA0: needs B0 (f0 >= 2it+1) ----
        WAITW(f0, 2 * it + 1);
        {
            float Sc = sumpassW(sx00, sx10, sx20, sy00, sy10, sy20, Bf + base0,
                                rloc, jh, lane, w, 4 * it + 1, pcomb, pflag);
            Aval0 = LMU - __log2f(Sc);
            if (lane < 8 && jh == 0) DSTORE(&Af[base0 + rloc + rr], Aval0);
        }
        POSTW(f0, 2 * it + 2);
        // ---- fA1: needs B1 (f1 >= 2it+1) ----
        WAITW(f1, 2 * it + 1);
        {
            float Sc = sumpassW(sx01, sx11, sx21, sy01, sy11, sy21, Bf + base1,
                                rloc, jh, lane, w, 4 * it + 2, pcomb, pflag);
            Aval1 = LMU - __log2f(Sc);
            if (lane < 8 && jh == 0) DSTORE(&Af[base1 + rloc + rr], Aval1);
        }
        POSTW(f1, 2 * it + 2);
        // ---- gB0: needs A0 (f0 >= 2it+2) ----
        WAITW(f0, 2 * it + 2);
        {
            float Sc = sumpassW(sy00, sy10, sy20, sx00, sx10, sx20, Af + base0,
                                rloc, jh, lane, w, 4 * it + 3, pcomb, pflag);
            if (lane < 8 && jh == 0)
                DSTORE(&Bf[base0 + rloc + rr], LMU - __log2f(Sc));
        }
        POSTW(f0, 2 * it + 3);
        // ---- gB1: needs A1 (f1 >= 2it+2) ----
        WAITW(f1, 2 * it + 2);
        {
            float Sc = sumpassW(sy01, sy11, sy21, sx01, sx11, sx21, Af + base1,
                                rloc, jh, lane, w, 4 * it + 4, pcomb, pflag);
            if (lane < 8 && jh == 0)
                DSTORE(&Bf[base1 + rloc + rr], LMU - __log2f(Sc));
        }
        POSTW(f1, 2 * it + 3);
    }
    // final B0/B1 for the epilogue
    WAITW(f0, 2 * NITERS + 1);
    WAITW(f1, 2 * NITERS + 1);

    // ---- epilogue: own 64 rows of each batch, own j-half ----
    {
        float s = epilG(sx00, sx10, sx20, sy00, sy10, sy20, Bf + base0,
                        Aval0, rloc, jh, lane)
                + epilG(sx01, sx11, sx21, sy01, sy11, sy21, Bf + base1,
                        Aval1, rloc, jh, lane);
        #pragma unroll
        for (int m = 32; m > 0; m >>= 1) s += __shfl_xor(s, m, 64);
        if (lane == 0) wsum[w] = s;
        __syncthreads();
        if (tid == 0) {
            float t = 0.f;
            #pragma unroll
            for (int i = 0; i < 16; ++i) t += wsum[i];
            atomicAdd(out, t * (1.0f / (float)BB));
        }
    }
    #undef WAITW
    #undef POSTW
}

extern "C" void kernel_launch(void* const* d_in, const int* in_sizes, int n_in,
                              void* d_out, int out_size, void* d_ws, size_t ws_size,
                              hipStream_t stream) {
    const float* x = (const float*)d_in[0];
    const float* y = (const float*)d_in[1];
    float* out = (float*)d_out;
    char* ws = (char*)d_ws;

    int*   flags = (int*)ws;                                 // 16 x 256 x 16 B = 64 KB
    float* Af    = (float*)(ws + 65536);                     // 128 KB
    float* Bf    = (float*)(ws + 65536 + (size_t)BB*NN*sizeof(float));

    hipMemsetAsync(flags, 0, 65536, stream);
    hipMemsetAsync(out, 0, sizeof(float), stream);

    const size_t shmem = (size_t)12 * NN * sizeof(float);    // 96 KB
    hipFuncSetAttribute((const void*)emd_sinkhorn,
                        hipFuncAttributeMaxDynamicSharedMemorySize, (int)shmem);

    void* args[] = {(void*)&x, (void*)&y, (void*)&Af, (void*)&Bf,
                    (void*)&flags, (void*)&out};
    hipError_t e = hipLaunchCooperativeKernel((const void*)emd_sinkhorn,
                                              dim3(256), dim3(1024),
                                              args, shmem, stream);
    if (e != hipSuccess) {
        hipLaunchKernelGGL(emd_sinkhorn, dim3(256), dim3(1024), shmem, stream,
                           x, y, Af, Bf, flags, out);
    }
}

// Round 15
// 7083.022 us; speedup vs baseline: 1.3409x; 1.3409x over previous
//
#include <hip/hip_runtime.h>

#define BB 16
#define NN 2048
#define NITERS 100

// k = log2(e)/eps, eps = 0.05
#define K2E      28.853900817779268f
#define TWO_K2E  57.707801635558536f
#define INV2K    0.017328679513998632f   // 1/(2k)
#define INV_K2E  0.034657359027997264f
#define INV4K    0.008664339756999316f   // 1/(4k)
#define LMU      (-11.0f)                // log2(1/2048)

#if __has_builtin(__builtin_amdgcn_exp2f)
#define EXP2F(x) __builtin_amdgcn_exp2f(x)
#else
#define EXP2F(x) exp2f(x)
#endif

typedef float v2f __attribute__((ext_vector_type(2)));

// device-coherent (LLC-homed, sc1) accessors for the dual arrays
#define DSTORE(p, v) __hip_atomic_store((p), (v), __ATOMIC_RELAXED, __HIP_MEMORY_SCOPE_AGENT)
#define DLOAD(p)     __hip_atomic_load((p), __ATOMIC_RELAXED, __HIP_MEMORY_SCOPE_AGENT)

// Sum-pass (R13-verified): 8 rows/wave (coords from LDS, raw = u*INV2K),
// own j-half of LDS SoA tables; dual read directly from LLC (sc1, 16
// preloads). Packed-f32 d-computation. One internal block sync (pcomb).
// Returns combined row-sum on lanes 0..7.
__device__ __forceinline__ float sumpassG(
    const float* __restrict__ u0, const float* __restrict__ u1,
    const float* __restrict__ u2,
    const float* __restrict__ t0, const float* __restrict__ t1,
    const float* __restrict__ t2, const float* __restrict__ gd,
    int rloc, int jh, int lane, int w, float* pcomb)
{
    const int jb = (jh << 10) + lane;
    float dv[16];
    #pragma unroll
    for (int s = 0; s < 16; ++s)
        dv[s] = DLOAD(gd + jb + (s << 6));

    v2f xp0[4], xp1[4], xp2[4], acc2[4];
    #pragma unroll
    for (int p = 0; p < 4; ++p) {
        xp0[p] = (v2f){u0[rloc + 2*p] * INV2K, u0[rloc + 2*p + 1] * INV2K};
        xp1[p] = (v2f){u1[rloc + 2*p] * INV2K, u1[rloc + 2*p + 1] * INV2K};
        xp2[p] = (v2f){u2[rloc + 2*p] * INV2K, u2[rloc + 2*p + 1] * INV2K};
        acc2[p] = (v2f){0.f, 0.f};
    }
    #pragma unroll 2
    for (int s = 0; s < 16; ++s) {
        const int p = jb + (s << 6);
        const float a0 = t0[p], a1 = t1[p], a2 = t2[p], ad = dv[s];
        const v2f a0v = (v2f){a0, a0}, a1v = (v2f){a1, a1};
        const v2f a2v = (v2f){a2, a2}, adv = (v2f){ad, ad};
        #pragma unroll
        for (int q = 0; q < 4; ++q) {
            v2f d = __builtin_elementwise_fma(xp0[q], a0v,
                    __builtin_elementwise_fma(xp1[q], a1v,
                    __builtin_elementwise_fma(xp2[q], a2v, adv)));
            acc2[q] += (v2f){EXP2F(d.x), EXP2F(d.y)};
        }
    }
    float acc[8];
    #pragma unroll
    for (int p = 0; p < 4; ++p) { acc[2*p] = acc2[p].x; acc[2*p+1] = acc2[p].y; }
    // multi-value butterfly (verified R3/R5/R8); lanes<8 end with row rr
    const bool b0 = lane & 1, b1 = lane & 2, b2 = lane & 4;
    float v4[4], v2_[2], v1;
    #pragma unroll
    for (int i = 0; i < 4; ++i) {
        float recv = __shfl_xor(b0 ? acc[i] : acc[i+4], 1, 64);
        v4[i] = (b0 ? acc[i+4] : acc[i]) + recv;
    }
    #pragma unroll
    for (int i = 0; i < 2; ++i) {
        float recv = __shfl_xor(b1 ? v4[i] : v4[i+2], 2, 64);
        v2_[i] = (b1 ? v4[i+2] : v4[i]) + recv;
    }
    {
        float recv = __shfl_xor(b2 ? v2_[0] : v2_[1], 4, 64);
        v1 = (b2 ? v2_[1] : v2_[0]) + recv;
    }
    v1 += __shfl_xor(v1, 8, 64);
    v1 += __shfl_xor(v1, 16, 64);
    v1 += __shfl_xor(v1, 32, 64);
    const int rr = ((lane & 1) << 2) | (lane & 2) | ((lane >> 2) & 1);
    if (lane < 8) pcomb[w * 8 + rr] = v1;
    __syncthreads();
    float S = 0.f;
    if (lane < 8) S = v1 + pcomb[(w ^ 1) * 8 + rr];
    return S;
}

// Epilogue partial (R13-verified): sum_j P_ij*C_ij, 8 rows x own j-half.
__device__ __forceinline__ float epilG(
    const float* __restrict__ u0, const float* __restrict__ u1,
    const float* __restrict__ u2,
    const float* __restrict__ t0, const float* __restrict__ t1,
    const float* __restrict__ t2, const float* __restrict__ gB,
    float Aval, int rloc, int jh, int lane)
{
    const int jb = (jh << 10) + lane;
    float dv[16];
    #pragma unroll
    for (int s = 0; s < 16; ++s)
        dv[s] = DLOAD(gB + jb + (s << 6));

    float xr0[8], xr1[8], xr2[8], Ak[8], x2k[8];
    #pragma unroll
    for (int k = 0; k < 8; ++k) {
        xr0[k] = u0[rloc + k] * INV2K;
        xr1[k] = u1[rloc + k] * INV2K;
        xr2[k] = u2[rloc + k] * INV2K;
        const int src = ((k & 1) << 2) | (k & 2) | ((k >> 2) & 1);
        Ak[k]  = __shfl(Aval, src, 64);
        x2k[k] = K2E * (xr0[k]*xr0[k] + xr1[k]*xr1[k] + xr2[k]*xr2[k]);
    }
    float acc = 0.f;
    for (int s = 0; s < 16; ++s) {
        const int p = jb + (s << 6);
        const float a0 = t0[p], a1 = t1[p], a2 = t2[p], tb = dv[s];
        const float q2 = (a0*a0 + a1*a1 + a2*a2) * INV4K;   // k|y|^2
        #pragma unroll
        for (int k = 0; k < 8; ++k) {
            float d = fmaf(xr0[k], a0, fmaf(xr1[k], a1, fmaf(xr2[k], a2, tb)));
            float P = EXP2F(d + Ak[k]);                       // exp(logP)
            float C = fmaxf((x2k[k] + q2 - (d - tb)) * INV_K2E, 0.f);
            acc = fmaf(P, C, acc);
        }
    }
    return acc;
}

// grid: 256 blocks x 1024 threads (1 block/CU). pair-of-batches = blk&7.
// R13 schedule and block lockstep, but the pre-post block barrier is gone:
// each PAIR's jh==0 lane0 release-posts its own global slot (256 slots x
// 16 B per batch) right after its 8 sc1 dual stores — the release drains
// exactly the stores that matter; the pair handshake proves the partner
// consumed its inputs. Detection stays centralized (wave 0 polls all 256
// slots, 4 sc1 loads/lane + ballot) + one resume sync. 2 syncs/phase.
__global__ __launch_bounds__(1024) void emd_sinkhorn(
    const float* __restrict__ x, const float* __restrict__ y,
    float* __restrict__ Af, float* __restrict__ Bf,
    int* __restrict__ flags, float* __restrict__ out)
{
    extern __shared__ float S[];     // 12*NN floats = 96 KB
    __shared__ float pcomb[16 * 8];
    __shared__ float wsum[16];

    const int tid  = threadIdx.x;
    const int lane = tid & 63;
    const int w    = tid >> 6;        // 0..15
    const int pr   = w >> 1;          // wave-pair 0..7
    const int jh   = w & 1;           // j-half
    const int blk  = blockIdx.x;
    const int pair = blk & 7;         // = XCD id under round-robin (perf only)
    const int q    = blk >> 3;        // 0..31: row-slice within pair
    const int b0   = pair * 2, b1 = b0 + 1;
    const int base0 = b0 * NN, base1 = b1 * NN;
    const int rloc  = q * 64 + pr * 8;      // within-batch row base
    const int slot  = q * 8 + pr;           // my pair's flag slot (0..255)
    int* f0 = flags + b0 * 1024;      // 256 slots x 16 B per batch
    int* f1 = flags + b1 * 1024;

    // LDS carve: per batch 6 table slots of NN floats (SoA — conflict-free)
    float *sy00 = S,            *sy10 = S +  1*NN, *sy20 = S +  2*NN;
    float *sx00 = S +  3*NN,    *sx10 = S +  4*NN, *sx20 = S +  5*NN;
    float *sy01 = S +  6*NN,    *sy11 = S +  7*NN, *sy21 = S +  8*NN;
    float *sx01 = S +  9*NN,    *sx11 = S + 10*NN, *sx21 = S + 11*NN;

    // ---- prologue: stage 2k-scaled tables ----
    #pragma unroll
    for (int v = 0; v < 2; ++v) {
        const int p = tid + (v << 10);
        {
            const float* px = x + 3 * (size_t)(base0 + p);
            sx00[p] = TWO_K2E * px[0]; sx10[p] = TWO_K2E * px[1]; sx20[p] = TWO_K2E * px[2];
            const float* py = y + 3 * (size_t)(base0 + p);
            sy00[p] = TWO_K2E * py[0]; sy10[p] = TWO_K2E * py[1]; sy20[p] = TWO_K2E * py[2];
        }
        {
            const float* px = x + 3 * (size_t)(base1 + p);
            sx01[p] = TWO_K2E * px[0]; sx11[p] = TWO_K2E * px[1]; sx21[p] = TWO_K2E * px[2];
            const float* py = y + 3 * (size_t)(base1 + p);
            sy01[p] = TWO_K2E * py[0]; sy11[p] = TWO_K2E * py[1]; sy21[p] = TWO_K2E * py[2];
        }
    }
    // ---- prologue: B0-init for own 64 columns of both batches (sc1) ----
    if (tid < 128) {
        const int bb  = tid >> 6;
        const int col = q * 64 + (tid & 63);
        const int bs  = bb ? base1 : base0;
        const float* py = y + 3 * (size_t)(bs + col);
        const float a = py[0], b = py[1], c = py[2];
        DSTORE(&Bf[bs + col], -K2E * (a*a + b*b + c*c));
    }
    __syncthreads();                  // drains all table + B-init stores
    if (w == 0 && lane < 16) {        // post value 1 for all 8 pairs, both batches
        int* arr = (lane < 8) ? f0 : f1;
        __hip_atomic_store(arr + (q * 8 + (lane & 7)) * 4, 1, __ATOMIC_RELEASE,
                           __HIP_MEMORY_SCOPE_AGENT);
    }

    const int rr = ((lane & 1) << 2) | (lane & 2) | ((lane >> 2) & 1);

    // block wait: wave 0 polls all 256 slots of arr >= tgt, then resume sync
    #define WAITB(arr, tgt) do {                                                \
        if (w == 0) {                                                           \
            for (;;) {                                                          \
                int a_ = __hip_atomic_load((arr) + lane * 4,         __ATOMIC_RELAXED, __HIP_MEMORY_SCOPE_AGENT); \
                int b_ = __hip_atomic_load((arr) + (lane +  64) * 4, __ATOMIC_RELAXED, __HIP_MEMORY_SCOPE_AGENT); \
                int c_ = __hip_atomic_load((arr) + (lane + 128) * 4, __ATOMIC_RELAXED, __HIP_MEMORY_SCOPE_AGENT); \
                int d_ = __hip_atomic_load((arr) + (lane + 192) * 4, __ATOMIC_RELAXED, __HIP_MEMORY_SCOPE_AGENT); \
                int m_ = min(min(a_, b_), min(c_, d_));                         \
                if (__ballot(m_ >= (tgt)) == ~0ULL) break;                      \
                __builtin_amdgcn_s_sleep(1);                                    \
            }                                                                   \
        }                                                                       \
        __syncthreads(); } while (0)

    // per-pair post: jh==0 lane0, release drains its own dual stores
    #define POSTP(arr, val) do {                                                \
        if (jh == 0 && lane == 0)                                               \
            __hip_atomic_store((arr) + slot * 4, (val), __ATOMIC_RELEASE,       \
                               __HIP_MEMORY_SCOPE_AGENT);                       \
    } while (0)

    float Aval0 = 0.f, Aval1 = 0.f;

    for (int it = 0; it < NITERS; ++it) {
        // ---- fA0: needs B0 (f0 >= 2it+1) ----
        WAITB(f0, 2 * it + 1);
        {
            float Sc = sumpassG(sx00, sx10, sx20, sy00, sy10, sy20, Bf + base0,
                                rloc, jh, lane, w, pcomb);
            Aval0 = LMU - __log2f(Sc);
            if (lane < 8 && jh == 0) DSTORE(&Af[base0 + rloc + rr], Aval0);
        }
        POSTP(f0, 2 * it + 2);
        // ---- fA1: needs B1 (f1 >= 2it+1) ----
        WAITB(f1, 2 * it + 1);
        {
            float Sc = sumpassG(sx01, sx11, sx21, sy01, sy11, sy21, Bf + base1,
                                rloc, jh, lane, w, pcomb);
            Aval1 = LMU - __log2f(Sc);
            if (lane < 8 && jh == 0) DSTORE(&Af[base1 + rloc + rr], Aval1);
        }
        POSTP(f1, 2 * it + 2);
        // ---- gB0: needs all A0 (f0 >= 2it+2; also proves Bf0 reads done) ----
        WAITB(f0, 2 * it + 2);
        {
            float Sc = sumpassG(sy00, sy10, sy20, sx00, sx10, sx20, Af + base0,
                                rloc, jh, lane, w, pcomb);
            if (lane < 8 && jh == 0)
                DSTORE(&Bf[base0 + rloc + rr], LMU - __log2f(Sc));
        }
        POSTP(f0, 2 * it + 3);
        // ---- gB1: needs all A1 (f1 >= 2it+2) ----
        WAITB(f1, 2 * it + 2);
        {
            float Sc = sumpassG(sy01, sy11, sy21, sx01, sx11, sx21, Af + base1,
                                rloc, jh, lane, w, pcomb);
            if (lane < 8 && jh == 0)
                DSTORE(&Bf[base1 + rloc + rr], LMU - __log2f(Sc));
        }
        POSTP(f1, 2 * it + 3);
    }
    // final B0/B1 for the epilogue
    WAITB(f0, 2 * NITERS + 1);
    WAITB(f1, 2 * NITERS + 1);

    // ---- epilogue: own 64 rows of each batch, own j-half ----
    {
        float s = epilG(sx00, sx10, sx20, sy00, sy10, sy20, Bf + base0,
                        Aval0, rloc, jh, lane)
                + epilG(sx01, sx11, sx21, sy01, sy11, sy21, Bf + base1,
                        Aval1, rloc, jh, lane);
        #pragma unroll
        for (int m = 32; m > 0; m >>= 1) s += __shfl_xor(s, m, 64);
        if (lane == 0) wsum[w] = s;
        __syncthreads();
        if (tid == 0) {
            float t = 0.f;
            #pragma unroll
            for (int i = 0; i < 16; ++i) t += wsum[i];
            atomicAdd(out, t * (1.0f / (float)BB));
        }
    }
    #undef WAITB
    #undef POSTP
}

extern "C" void kernel_launch(void* const* d_in, const int* in_sizes, int n_in,
                              void* d_out, int out_size, void* d_ws, size_t ws_size,
                              hipStream_t stream) {
    const float* x = (const float*)d_in[0];
    const float* y = (const float*)d_in[1];
    float* out = (float*)d_out;
    char* ws = (char*)d_ws;

    int*   flags = (int*)ws;                                 // 16 x 256 x 16 B = 64 KB
    float* Af    = (float*)(ws + 65536);                     // 128 KB
    float* Bf    = (float*)(ws + 65536 + (size_t)BB*NN*sizeof(float));

    hipMemsetAsync(flags, 0, 65536, stream);
    hipMemsetAsync(out, 0, sizeof(float), stream);

    const size_t shmem = (size_t)12 * NN * sizeof(float);    // 96 KB
    hipFuncSetAttribute((const void*)emd_sinkhorn,
                        hipFuncAttributeMaxDynamicSharedMemorySize, (int)shmem);

    void* args[] = {(void*)&x, (void*)&y, (void*)&Af, (void*)&Bf,
                    (void*)&flags, (void*)&out};
    hipError_t e = hipLaunchCooperativeKernel((const void*)emd_sinkhorn,
                                              dim3(256), dim3(1024),
                                              args, shmem, stream);
    if (e != hipSuccess) {
        hipLaunchKernelGGL(emd_sinkhorn, dim3(256), dim3(1024), shmem, stream,
                           x, y, Af, Bf, flags, out);
    }
}

// Round 16
// 2961.715 us; speedup vs baseline: 3.2068x; 2.3915x over previous
//
#include <hip/hip_runtime.h>

#define BB 16
#define NN 2048
#define NITERS 100

// k = log2(e)/eps, eps = 0.05
#define K2E      28.853900817779268f
#define TWO_K2E  57.707801635558536f
#define INV2K    0.017328679513998632f   // 1/(2k)
#define INV_K2E  0.034657359027997264f
#define INV4K    0.008664339756999316f   // 1/(4k)
#define LMU      (-11.0f)                // log2(1/2048)

#if __has_builtin(__builtin_amdgcn_exp2f)
#define EXP2F(x) __builtin_amdgcn_exp2f(x)
#else
#define EXP2F(x) exp2f(x)
#endif

typedef float v2f __attribute__((ext_vector_type(2)));

// device-coherent (LLC-homed, sc1) accessors for the dual arrays
#define DSTORE(p, v) __hip_atomic_store((p), (v), __ATOMIC_RELAXED, __HIP_MEMORY_SCOPE_AGENT)
#define DLOAD(p)     __hip_atomic_load((p), __ATOMIC_RELAXED, __HIP_MEMORY_SCOPE_AGENT)

// Sum-pass (R13-verified): 8 rows/wave (coords from LDS, raw = u*INV2K),
// own j-half of LDS SoA tables; dual read directly from LLC (sc1, 16
// preloads, latency hidden under compute + 16-wave TLP). Packed-f32
// d-computation. Returns combined row-sum on lanes 0..7.
__device__ __forceinline__ float sumpassG(
    const float* __restrict__ u0, const float* __restrict__ u1,
    const float* __restrict__ u2,
    const float* __restrict__ t0, const float* __restrict__ t1,
    const float* __restrict__ t2, const float* __restrict__ gd,
    int rloc, int jh, int lane, int w, float* pcomb)
{
    const int jb = (jh << 10) + lane;
    float dv[16];
    #pragma unroll
    for (int s = 0; s < 16; ++s)
        dv[s] = DLOAD(gd + jb + (s << 6));

    v2f xp0[4], xp1[4], xp2[4], acc2[4];
    #pragma unroll
    for (int p = 0; p < 4; ++p) {
        xp0[p] = (v2f){u0[rloc + 2*p] * INV2K, u0[rloc + 2*p + 1] * INV2K};
        xp1[p] = (v2f){u1[rloc + 2*p] * INV2K, u1[rloc + 2*p + 1] * INV2K};
        xp2[p] = (v2f){u2[rloc + 2*p] * INV2K, u2[rloc + 2*p + 1] * INV2K};
        acc2[p] = (v2f){0.f, 0.f};
    }
    #pragma unroll 2
    for (int s = 0; s < 16; ++s) {
        const int p = jb + (s << 6);
        const float a0 = t0[p], a1 = t1[p], a2 = t2[p], ad = dv[s];
        const v2f a0v = (v2f){a0, a0}, a1v = (v2f){a1, a1};
        const v2f a2v = (v2f){a2, a2}, adv = (v2f){ad, ad};
        #pragma unroll
        for (int q = 0; q < 4; ++q) {
            v2f d = __builtin_elementwise_fma(xp0[q], a0v,
                    __builtin_elementwise_fma(xp1[q], a1v,
                    __builtin_elementwise_fma(xp2[q], a2v, adv)));
            acc2[q] += (v2f){EXP2F(d.x), EXP2F(d.y)};
        }
    }
    float acc[8];
    #pragma unroll
    for (int p = 0; p < 4; ++p) { acc[2*p] = acc2[p].x; acc[2*p+1] = acc2[p].y; }
    // multi-value butterfly (verified R3/R5/R8); lanes<8 end with row rr
    const bool b0 = lane & 1, b1 = lane & 2, b2 = lane & 4;
    float v4[4], v2_[2], v1;
    #pragma unroll
    for (int i = 0; i < 4; ++i) {
        float recv = __shfl_xor(b0 ? acc[i] : acc[i+4], 1, 64);
        v4[i] = (b0 ? acc[i+4] : acc[i]) + recv;
    }
    #pragma unroll
    for (int i = 0; i < 2; ++i) {
        float recv = __shfl_xor(b1 ? v4[i] : v4[i+2], 2, 64);
        v2_[i] = (b1 ? v4[i+2] : v4[i]) + recv;
    }
    {
        float recv = __shfl_xor(b2 ? v2_[0] : v2_[1], 4, 64);
        v1 = (b2 ? v2_[1] : v2_[0]) + recv;
    }
    v1 += __shfl_xor(v1, 8, 64);
    v1 += __shfl_xor(v1, 16, 64);
    v1 += __shfl_xor(v1, 32, 64);
    const int rr = ((lane & 1) << 2) | (lane & 2) | ((lane >> 2) & 1);
    if (lane < 8) pcomb[w * 8 + rr] = v1;
    __syncthreads();
    float S = 0.f;
    if (lane < 8) S = v1 + pcomb[(w ^ 1) * 8 + rr];
    return S;
}

// Epilogue partial (R13-verified): sum_j P_ij*C_ij, 8 rows x own j-half.
__device__ __forceinline__ float epilG(
    const float* __restrict__ u0, const float* __restrict__ u1,
    const float* __restrict__ u2,
    const float* __restrict__ t0, const float* __restrict__ t1,
    const float* __restrict__ t2, const float* __restrict__ gB,
    float Aval, int rloc, int jh, int lane)
{
    const int jb = (jh << 10) + lane;
    float dv[16];
    #pragma unroll
    for (int s = 0; s < 16; ++s)
        dv[s] = DLOAD(gB + jb + (s << 6));

    float xr0[8], xr1[8], xr2[8], Ak[8], x2k[8];
    #pragma unroll
    for (int k = 0; k < 8; ++k) {
        xr0[k] = u0[rloc + k] * INV2K;
        xr1[k] = u1[rloc + k] * INV2K;
        xr2[k] = u2[rloc + k] * INV2K;
        const int src = ((k & 1) << 2) | (k & 2) | ((k >> 2) & 1);
        Ak[k]  = __shfl(Aval, src, 64);
        x2k[k] = K2E * (xr0[k]*xr0[k] + xr1[k]*xr1[k] + xr2[k]*xr2[k]);
    }
    float acc = 0.f;
    for (int s = 0; s < 16; ++s) {
        const int p = jb + (s << 6);
        const float a0 = t0[p], a1 = t1[p], a2 = t2[p], tb = dv[s];
        const float q2 = (a0*a0 + a1*a1 + a2*a2) * INV4K;   // k|y|^2
        #pragma unroll
        for (int k = 0; k < 8; ++k) {
            float d = fmaf(xr0[k], a0, fmaf(xr1[k], a1, fmaf(xr2[k], a2, tb)));
            float P = EXP2F(d + Ak[k]);                       // exp(logP)
            float C = fmaxf((x2k[k] + q2 - (d - tb)) * INV_K2E, 0.f);
            acc = fmaf(P, C, acc);
        }
    }
    return acc;
}

// grid: 256 blocks x 1024 threads (1 block/CU). pair-of-batches = blk&7.
// R13-verified structure: deterministic software pipeline (one compute
// phase of slack before every wait), duals LLC-homed (sc1) consumed inside
// the compute loop, block-centralized exchange: tid0 posts the block's slot
// (32 slots x 16 B per batch), wave 0 polls all 32 slots in parallel
// (ballot), fused post+wait between two block syncs. Block lockstep is
// load-bearing (R14/R15: decentralizing waits or posts regresses 2-3x).
__global__ __launch_bounds__(1024) void emd_sinkhorn(
    const float* __restrict__ x, const float* __restrict__ y,
    float* __restrict__ Af, float* __restrict__ Bf,
    int* __restrict__ flags, float* __restrict__ out)
{
    extern __shared__ float S[];     // 12*NN floats = 96 KB
    __shared__ float pcomb[16 * 8];
    __shared__ float wsum[16];

    const int tid  = threadIdx.x;
    const int lane = tid & 63;
    const int w    = tid >> 6;        // 0..15
    const int pr   = w >> 1;          // wave-pair 0..7
    const int jh   = w & 1;           // j-half
    const int blk  = blockIdx.x;
    const int pair = blk & 7;         // = XCD id under round-robin (perf only)
    const int q    = blk >> 3;        // 0..31: row-slice within pair
    const int b0   = pair * 2, b1 = b0 + 1;
    const int base0 = b0 * NN, base1 = b1 * NN;
    const int rloc  = q * 64 + pr * 8;      // within-batch row base
    int* f0 = flags + b0 * 128;       // 32 slots x 16 B per batch
    int* f1 = flags + b1 * 128;

    // LDS carve: per batch 6 table slots of NN floats (SoA — conflict-free)
    float *sy00 = S,            *sy10 = S +  1*NN, *sy20 = S +  2*NN;
    float *sx00 = S +  3*NN,    *sx10 = S +  4*NN, *sx20 = S +  5*NN;
    float *sy01 = S +  6*NN,    *sy11 = S +  7*NN, *sy21 = S +  8*NN;
    float *sx01 = S +  9*NN,    *sx11 = S + 10*NN, *sx21 = S + 11*NN;

    // ---- prologue: stage 2k-scaled tables ----
    #pragma unroll
    for (int v = 0; v < 2; ++v) {
        const int p = tid + (v << 10);
        {
            const float* px = x + 3 * (size_t)(base0 + p);
            sx00[p] = TWO_K2E * px[0]; sx10[p] = TWO_K2E * px[1]; sx20[p] = TWO_K2E * px[2];
            const float* py = y + 3 * (size_t)(base0 + p);
            sy00[p] = TWO_K2E * py[0]; sy10[p] = TWO_K2E * py[1]; sy20[p] = TWO_K2E * py[2];
        }
        {
            const float* px = x + 3 * (size_t)(base1 + p);
            sx01[p] = TWO_K2E * px[0]; sx11[p] = TWO_K2E * px[1]; sx21[p] = TWO_K2E * px[2];
            const float* py = y + 3 * (size_t)(base1 + p);
            sy01[p] = TWO_K2E * py[0]; sy11[p] = TWO_K2E * py[1]; sy21[p] = TWO_K2E * py[2];
        }
    }
    // ---- prologue: B0-init for own 64 columns of both batches (sc1) ----
    if (tid < 128) {
        const int bb  = tid >> 6;
        const int col = q * 64 + (tid & 63);
        const int bs  = bb ? base1 : base0;
        const float* py = y + 3 * (size_t)(bs + col);
        const float a = py[0], b = py[1], c = py[2];
        DSTORE(&Bf[bs + col], -K2E * (a*a + b*b + c*c));
    }
    __syncthreads();                  // drains table + B-init stores
    if (tid == 0) {
        __hip_atomic_store(f0 + q * 4, 1, __ATOMIC_RELEASE, __HIP_MEMORY_SCOPE_AGENT);
        __hip_atomic_store(f1 + q * 4, 1, __ATOMIC_RELEASE, __HIP_MEMORY_SCOPE_AGENT);
    }

    const int rr = ((lane & 1) << 2) | (lane & 2) | ((lane >> 2) & 1);

    // post own phase into own slot + wait all 32 slots of the other array
    #define PW(pslot, pval, warr, tgt) do { __syncthreads();                    \
        if (tid == 0)                                                           \
            __hip_atomic_store((pslot), (pval), __ATOMIC_RELEASE,               \
                               __HIP_MEMORY_SCOPE_AGENT);                       \
        if (w == 0) {                                                           \
            for (;;) {                                                          \
                int vv = (lane < 32)                                            \
                    ? __hip_atomic_load((warr) + lane * 4, __ATOMIC_RELAXED,    \
                                        __HIP_MEMORY_SCOPE_AGENT)               \
                    : 0x7fffffff;                                               \
                if (__ballot(vv >= (tgt)) == ~0ULL) break;                      \
                __builtin_amdgcn_s_sleep(1);                                    \
            }                                                                   \
        }                                                                       \
        __syncthreads(); } while (0)

    #define WONLY(warr, tgt) do { __syncthreads();                              \
        if (w == 0) {                                                           \
            for (;;) {                                                          \
                int vv = (lane < 32)                                            \
                    ? __hip_atomic_load((warr) + lane * 4, __ATOMIC_RELAXED,    \
                                        __HIP_MEMORY_SCOPE_AGENT)               \
                    : 0x7fffffff;                                               \
                if (__ballot(vv >= (tgt)) == ~0ULL) break;                      \
                __builtin_amdgcn_s_sleep(1);                                    \
            }                                                                   \
        }                                                                       \
        __syncthreads(); } while (0)

    WONLY(f0, 1);                     // initial B0 ready (one-time, low slack)

    float Aval0 = 0.f, Aval1 = 0.f;

    for (int it = 0; it < NITERS; ++it) {
        // ---- fA0: dual = Bf[batch0] ----
        {
            float Sc = sumpassG(sx00, sx10, sx20, sy00, sy10, sy20, Bf + base0,
                                rloc, jh, lane, w, pcomb);
            Aval0 = LMU - __log2f(Sc);
            if (lane < 8 && jh == 0) DSTORE(&Af[base0 + rloc + rr], Aval0);
        }
        PW(f0 + q * 4, 2 * it + 2, f1, 2 * it + 1);   // post A0; wait B1
        // ---- fA1 ----
        {
            float Sc = sumpassG(sx01, sx11, sx21, sy01, sy11, sy21, Bf + base1,
                                rloc, jh, lane, w, pcomb);
            Aval1 = LMU - __log2f(Sc);
            if (lane < 8 && jh == 0) DSTORE(&Af[base1 + rloc + rr], Aval1);
        }
        PW(f1 + q * 4, 2 * it + 2, f0, 2 * it + 2);   // post A1; wait A0
        // ---- gB0: dual = Af[batch0] ----
        {
            float Sc = sumpassG(sy00, sy10, sy20, sx00, sx10, sx20, Af + base0,
                                rloc, jh, lane, w, pcomb);
            if (lane < 8 && jh == 0)
                DSTORE(&Bf[base0 + rloc + rr], LMU - __log2f(Sc));
        }
        PW(f0 + q * 4, 2 * it + 3, f1, 2 * it + 2);   // post B0; wait A1
        // ---- gB1 ----
        {
            float Sc = sumpassG(sy01, sy11, sy21, sx01, sx11, sx21, Af + base1,
                                rloc, jh, lane, w, pcomb);
            if (lane < 8 && jh == 0)
                DSTORE(&Bf[base1 + rloc + rr], LMU - __log2f(Sc));
        }
        PW(f1 + q * 4, 2 * it + 3, f0, 2 * it + 3);   // post B1; wait B0-new
    }
    // epilogue needs final B1 too
    WONLY(f1, 2 * NITERS + 1);

    // ---- epilogue: own 64 rows of each batch, own j-half ----
    {
        float s = epilG(sx00, sx10, sx20, sy00, sy10, sy20, Bf + base0,
                        Aval0, rloc, jh, lane)
                + epilG(sx01, sx11, sx21, sy01, sy11, sy21, Bf + base1,
                        Aval1, rloc, jh, lane);
        #pragma unroll
        for (int m = 32; m > 0; m >>= 1) s += __shfl_xor(s, m, 64);
        if (lane == 0) wsum[w] = s;
        __syncthreads();
        if (tid == 0) {
            float t = 0.f;
            #pragma unroll
            for (int i = 0; i < 16; ++i) t += wsum[i];
            atomicAdd(out, t * (1.0f / (float)BB));
        }
    }
    #undef PW
    #undef WONLY
}

extern "C" void kernel_launch(void* const* d_in, const int* in_sizes, int n_in,
                              void* d_out, int out_size, void* d_ws, size_t ws_size,
                              hipStream_t stream) {
    const float* x = (const float*)d_in[0];
    const float* y = (const float*)d_in[1];
    float* out = (float*)d_out;
    char* ws = (char*)d_ws;

    int*   flags = (int*)ws;                                 // 16 x 32 x 16 B = 8 KB
    float* Af    = (float*)(ws + 8192);                      // 128 KB
    float* Bf    = (float*)(ws + 8192 + (size_t)BB*NN*sizeof(float));

    hipMemsetAsync(flags, 0, 8192, stream);
    hipMemsetAsync(out, 0, sizeof(float), stream);

    const size_t shmem = (size_t)12 * NN * sizeof(float);    // 96 KB
    hipFuncSetAttribute((const void*)emd_sinkhorn,
                        hipFuncAttributeMaxDynamicSharedMemorySize, (int)shmem);

    void* args[] = {(void*)&x, (void*)&y, (void*)&Af, (void*)&Bf,
                    (void*)&flags, (void*)&out};
    hipError_t e = hipLaunchCooperativeKernel((const void*)emd_sinkhorn,
                                              dim3(256), dim3(1024),
                                              args, shmem, stream);
    if (e != hipSuccess) {
        hipLaunchKernelGGL(emd_sinkhorn, dim3(256), dim3(1024), shmem, stream,
                           x, y, Af, Bf, flags, out);
    }
}